// Round 2
// baseline (1800.186 us; speedup 1.0000x reference)
//
#include <hip/hip_runtime.h>
#include <stdint.h>

#define N_SUBJ 128
#define CDIM 256
#define WSP 3000
#define BATCH 256

typedef __bf16 bf16x8 __attribute__((ext_vector_type(8)));
typedef float f32x4 __attribute__((ext_vector_type(4)));
typedef unsigned short us8 __attribute__((ext_vector_type(8)));

__device__ __forceinline__ unsigned short f2bf(float f) {
  unsigned u = __float_as_uint(f);
  u += 0x7FFFu + ((u >> 16) & 1u);
  return (unsigned short)(u >> 16);
}
__device__ __forceinline__ float bf2f(unsigned short h) {
  return __uint_as_float(((unsigned)h) << 16);
}

// ---------------- prepass: split weights into bf16 hi/lo ----------------
__global__ __launch_bounds__(256) void conv_w_kernel(
    const float* __restrict__ w, unsigned short* __restrict__ wh,
    unsigned short* __restrict__ wl) {
  size_t i = ((size_t)blockIdx.x * 256 + threadIdx.x) * 4;
  float4 v = *(const float4*)(w + i);
  float f[4] = {v.x, v.y, v.z, v.w};
  unsigned short h[4], l[4];
#pragma unroll
  for (int j = 0; j < 4; ++j) {
    h[j] = f2bf(f[j]);
    l[j] = f2bf(f[j] - bf2f(h[j]));
  }
  *(ushort4*)(wh + i) = make_ushort4(h[0], h[1], h[2], h[3]);
  *(ushort4*)(wl + i) = make_ushort4(l[0], l[1], l[2], l[3]);
}

// ---------------- main GEMM ----------------
// BM=256 (all c_out, so x is read exactly once), BN=64 spatial, BK=32,
// 4 waves, each wave owns a 64x64 output tile (4x4 frags of 16x16x32 bf16).
// Split-precision: out = xh*wh + xh*wl + xl*wh (fp32 accum), err ~3e-6.
template <bool PRE>
__global__ __launch_bounds__(256) void subj_gemm(
    const float* __restrict__ x, const float* __restrict__ weight,
    const float* __restrict__ bias, const int* __restrict__ subj,
    const unsigned short* __restrict__ gwh,
    const unsigned short* __restrict__ gwl, float* __restrict__ out) {
  constexpr int SW = 40;  // padded LDS k-stride (ushorts): 80B rows -> bank-balanced
  __shared__ __align__(16) unsigned short Wh[CDIM * SW];
  __shared__ __align__(16) unsigned short Wl[CDIM * SW];
  __shared__ __align__(16) unsigned short Xh[64 * SW];
  __shared__ __align__(16) unsigned short Xl[64 * SW];

  const int tid = threadIdx.x;
  const int lane = tid & 63;
  const int wv = tid >> 6;
  const int l15 = lane & 15;
  const int lg = lane >> 4;  // 0..3 -> k chunk of 8
  const int n0 = blockIdx.x * 64;
  const int b = blockIdx.y;

  // subj_indices may arrive as int32 (JAX default canonicalization) or true
  // int64 (x64 mode). Values are 0..127 and nonnegative, so for int64 the odd
  // int32 words are all zero; for int32 the odds are 6 independent random
  // indices -> P(all zero) = (1/128)^6 ~ 2e-13.
  const bool is64 = (subj[1] == 0) & (subj[3] == 0) & (subj[5] == 0) &
                    (subj[7] == 0) & (subj[9] == 0) & (subj[11] == 0);
  const int s = is64 ? subj[2 * b] : subj[b];

  f32x4 acc[4][4];
  const f32x4 zz = {0.f, 0.f, 0.f, 0.f};
#pragma unroll
  for (int i = 0; i < 4; ++i)
#pragma unroll
    for (int j = 0; j < 4; ++j) acc[i][j] = zz;

  // X staging coords: thread covers column n=(tid&63), k rows xk0..xk0+7
  const int xn = tid & 63;
  const int xk0 = (tid >> 6) * 8;
  const bool xvalid = (n0 + xn) < WSP;
  const float* xp = x + (size_t)b * CDIM * WSP + n0 + xn;

  const size_t wbase = (size_t)s << 16;  // s * 256 * 256

  for (int kt = 0; kt < 8; ++kt) {
    const int k0 = kt * 32;

    // ---- stage X (transpose [k][n] -> [n][k], fp32 -> bf16 hi/lo) ----
    {
      us8 hv, lv;
#pragma unroll
      for (int j = 0; j < 8; ++j) {
        float f = xvalid ? xp[(size_t)(k0 + xk0 + j) * WSP] : 0.f;
        unsigned short h = f2bf(f);
        hv[j] = h;
        lv[j] = f2bf(f - bf2f(h));
      }
      *(us8*)&Xh[xn * SW + xk0] = hv;
      *(us8*)&Xl[xn * SW + xk0] = lv;
    }

    // ---- stage W (row = tid, cols k0..k0+31) ----
    if (PRE) {
      const unsigned short* rh = gwh + wbase + (size_t)tid * CDIM + k0;
      const unsigned short* rl = gwl + wbase + (size_t)tid * CDIM + k0;
#pragma unroll
      for (int c = 0; c < 4; ++c) {
        *(us8*)&Wh[tid * SW + c * 8] = *(const us8*)(rh + c * 8);
        *(us8*)&Wl[tid * SW + c * 8] = *(const us8*)(rl + c * 8);
      }
    } else {
      const float* wr = weight + wbase + (size_t)tid * CDIM + k0;
      float wf[32];
#pragma unroll
      for (int c = 0; c < 8; ++c) {
        float4 v = *(const float4*)(wr + c * 4);
        wf[c * 4 + 0] = v.x;
        wf[c * 4 + 1] = v.y;
        wf[c * 4 + 2] = v.z;
        wf[c * 4 + 3] = v.w;
      }
#pragma unroll
      for (int c = 0; c < 4; ++c) {
        us8 hv, lv;
#pragma unroll
        for (int j = 0; j < 8; ++j) {
          float f = wf[c * 8 + j];
          unsigned short h = f2bf(f);
          hv[j] = h;
          lv[j] = f2bf(f - bf2f(h));
        }
        *(us8*)&Wh[tid * SW + c * 8] = hv;
        *(us8*)&Wl[tid * SW + c * 8] = lv;
      }
    }

    __syncthreads();

    // ---- fragments ----
    bf16x8 ah[4], al[4], bh[4], bl[4];
#pragma unroll
    for (int mf = 0; mf < 4; ++mf) {
      const int row = wv * 64 + mf * 16 + l15;
      ah[mf] = *(const bf16x8*)&Wh[row * SW + lg * 8];
      al[mf] = *(const bf16x8*)&Wl[row * SW + lg * 8];
    }
#pragma unroll
    for (int nf = 0; nf < 4; ++nf) {
      const int col = nf * 16 + l15;
      bh[nf] = *(const bf16x8*)&Xh[col * SW + lg * 8];
      bl[nf] = *(const bf16x8*)&Xl[col * SW + lg * 8];
    }

    // ---- MFMA, 3-term split: hh + hl + lh (16 independent acc chains) ----
#pragma unroll
    for (int mf = 0; mf < 4; ++mf)
#pragma unroll
      for (int nf = 0; nf < 4; ++nf) {
        acc[mf][nf] = __builtin_amdgcn_mfma_f32_16x16x32_bf16(
            ah[mf], bh[nf], acc[mf][nf], 0, 0, 0);
        acc[mf][nf] = __builtin_amdgcn_mfma_f32_16x16x32_bf16(
            ah[mf], bl[nf], acc[mf][nf], 0, 0, 0);
        acc[mf][nf] = __builtin_amdgcn_mfma_f32_16x16x32_bf16(
            al[mf], bh[nf], acc[mf][nf], 0, 0, 0);
      }

    __syncthreads();
  }

  // ---- epilogue: bias + store ----
  // C/D mapping (HW-verified m89/m91): col = lane&15, row = (lane>>4)*4 + j
#pragma unroll
  for (int mf = 0; mf < 4; ++mf) {
    const int rbase = wv * 64 + mf * 16 + lg * 4;
    float bv[4];
#pragma unroll
    for (int j = 0; j < 4; ++j) bv[j] = bias[s * CDIM + rbase + j];
#pragma unroll
    for (int nf = 0; nf < 4; ++nf) {
      const int col = n0 + nf * 16 + l15;
      if (col < WSP) {
#pragma unroll
        for (int j = 0; j < 4; ++j) {
          out[((size_t)b * CDIM + rbase + j) * WSP + col] =
              acc[mf][nf][j] + bv[j];
        }
      }
    }
  }
}

extern "C" void kernel_launch(void* const* d_in, const int* in_sizes, int n_in,
                              void* d_out, int out_size, void* d_ws,
                              size_t ws_size, hipStream_t stream) {
  const float* x = (const float*)d_in[0];
  const float* w = (const float*)d_in[1];
  const float* bias = (const float*)d_in[2];
  const int* subj = (const int*)d_in[3];
  float* out = (float*)d_out;

  const size_t wcnt = (size_t)N_SUBJ * CDIM * CDIM;        // 8,388,608
  const size_t need = wcnt * 2 * sizeof(unsigned short);   // 33.55 MB
  dim3 grid((WSP + 63) / 64, BATCH);                       // 47 x 256

  if (ws_size >= need) {
    unsigned short* wh = (unsigned short*)d_ws;
    unsigned short* wl = wh + wcnt;
    conv_w_kernel<<<(int)(wcnt / (256 * 4)), 256, 0, stream>>>(w, wh, wl);
    subj_gemm<true><<<grid, 256, 0, stream>>>(x, w, bias, subj, wh, wl, out);
  } else {
    subj_gemm<false><<<grid, 256, 0, stream>>>(x, w, bias, subj, nullptr,
                                               nullptr, out);
  }
}